// Round 1
// baseline (101.961 us; speedup 1.0000x reference)
//
#include <hip/hip_runtime.h>
#include <math.h>

#define B_ 2
#define N_ 512
#define C_ 32
#define H_ 200
#define W_ 200
#define THRESH_ 0.05f
#define OUT_BEV (B_*C_*H_*W_)

// power = a*du^2 + bb*dv^2 + cc*du*dv  with a=-0.5*Iuu, bb=-0.5*Ivv, cc=-Iuv
__device__ inline void compute_params(float x, float y, float c0, float c1, float c3,
                                      float op, float4& q0, float4& q1) {
    float mu_u = 100.0f - 100.0f * y;          // H/2 - SH*y
    float mu_v = 100.0f - 100.0f * x;          // W/2 - SW*x
    float Cuu = 10000.0f * c3 + 0.3f;          // SH^2*cov[3] + lowpass
    float Cvv = 10000.0f * c0 + 0.3f;          // SW^2*cov[0] + lowpass
    float Cuv = 10000.0f * c1;                 // SH*SW*cov[1]
    float det = Cuu * Cvv - Cuv * Cuv;
    bool valid = det > 0.0f;
    float opac = (op > THRESH_) ? op : 0.0f;
    if (!valid) opac = 0.0f;
    float inv_det = valid ? (1.0f / det) : 0.0f;
    float a  = -0.5f * (Cvv * inv_det);        // -0.5*Iuu
    float bb = -0.5f * (Cuu * inv_det);        // -0.5*Ivv
    float cc = Cuv * inv_det;                  // -Iuv = -(-Cuv*inv_det)
    // contribute iff power<=0 and opac*exp(power) >= 1/255  <=>  power >= thr
    float thr = (opac > 0.0f) ? logf(1.0f / (255.0f * opac)) : 3.0e38f;
    q0 = make_float4(mu_u, mu_v, a, bb);
    q1 = make_float4(cc, opac, thr, 0.0f);
}

// One block of 1024 threads: per-gaussian params -> d_ws (if available), plus
// the num_gaussians scalar (count of raw opac > THRESH, averaged over batch).
__global__ __launch_bounds__(1024) void precompute_kernel(
    const float* __restrict__ means3D,    // [B,N,3]
    const float* __restrict__ cov3D,      // [B,N,6]
    const float* __restrict__ opacities,  // [B,N,1]
    float4* __restrict__ params,          // [B*N*2] float4, may be null
    float* __restrict__ out_scalar)       // &d_out[OUT_BEV]
{
    int i = threadIdx.x;                  // i = b*N + n, 0..1023
    float x  = means3D[i*3 + 0];
    float y  = means3D[i*3 + 1];
    float c0 = cov3D[i*6 + 0];
    float c1 = cov3D[i*6 + 1];
    float c3 = cov3D[i*6 + 3];
    float op = opacities[i];

    if (params) {
        float4 q0, q1;
        compute_params(x, y, c0, c1, c3, op, q0, q1);
        params[2*i]     = q0;
        params[2*i + 1] = q1;
    }

    __shared__ int red[1024];
    red[i] = (op > THRESH_) ? 1 : 0;
    __syncthreads();
    for (int s = 512; s > 0; s >>= 1) {
        if (i < s) red[i] += red[i + s];
        __syncthreads();
    }
    if (i == 0) out_scalar[0] = (float)red[0] / (float)B_;
}

// One wave (64 threads) per 8x8 pixel tile. Params read from global with a
// uniform index -> scalar loads.
__global__ __launch_bounds__(64) void render_kernel(
    const float* __restrict__ features,   // [B,N,C]
    const float4* __restrict__ params,    // [B*N*2]
    float* __restrict__ out)              // [B,C,H,W]
{
    int blk = blockIdx.x;
    int b  = blk / 625;
    int t  = blk - b * 625;
    int tu = t / 25;
    int tv = t - tu * 25;
    int lane = threadIdx.x;
    int uu = tu * 8 + (lane >> 3);
    int vv = tv * 8 + (lane & 7);
    float u = (float)uu, v = (float)vv;

    float T = 1.0f;
    float acc[C_];
#pragma unroll
    for (int c = 0; c < C_; ++c) acc[c] = 0.0f;

    const float*  featB = features + (size_t)b * N_ * C_;
    const float4* pb    = params + (size_t)b * N_ * 2;

    for (int n = 0; n < N_; ++n) {
        float4 q0 = pb[2*n];
        float4 q1 = pb[2*n + 1];
        float du = u - q0.x;
        float dv = v - q0.y;
        float pw = fmaf(q0.z * du, du, fmaf(q0.w * dv, dv, q1.x * (du * dv)));
        bool hit = (pw <= 0.0f) && (pw >= q1.z);
        if (__any(hit)) {
            float e  = expf(pw);
            float al = hit ? fminf(0.99f, q1.y * e) : 0.0f;
            float w  = T * al;
            const float* f = featB + n * C_;
#pragma unroll
            for (int c = 0; c < C_; ++c) acc[c] = fmaf(w, f[c], acc[c]);
            T *= (1.0f - al);
        }
    }

    size_t obase = (size_t)b * C_ * H_ * W_ + (size_t)uu * W_ + vv;
#pragma unroll
    for (int c = 0; c < C_; ++c) out[obase + (size_t)c * (H_ * W_)] = acc[c];
}

// Fallback when ws is too small: params computed per-block into LDS.
__global__ __launch_bounds__(64) void render_kernel_lds(
    const float* __restrict__ features,
    const float* __restrict__ means3D,
    const float* __restrict__ cov3D,
    const float* __restrict__ opacities,
    float* __restrict__ out)
{
    __shared__ float4 p0[N_];
    __shared__ float4 p1[N_];

    int blk = blockIdx.x;
    int b  = blk / 625;
    int t  = blk - b * 625;
    int tu = t / 25;
    int tv = t - tu * 25;
    int lane = threadIdx.x;

    for (int n = lane; n < N_; n += 64) {
        int i = b * N_ + n;
        float4 q0, q1;
        compute_params(means3D[i*3+0], means3D[i*3+1],
                       cov3D[i*6+0], cov3D[i*6+1], cov3D[i*6+3],
                       opacities[i], q0, q1);
        p0[n] = q0;
        p1[n] = q1;
    }
    __syncthreads();

    int uu = tu * 8 + (lane >> 3);
    int vv = tv * 8 + (lane & 7);
    float u = (float)uu, v = (float)vv;

    float T = 1.0f;
    float acc[C_];
#pragma unroll
    for (int c = 0; c < C_; ++c) acc[c] = 0.0f;

    const float* featB = features + (size_t)b * N_ * C_;

    for (int n = 0; n < N_; ++n) {
        float4 q0 = p0[n];
        float4 q1 = p1[n];
        float du = u - q0.x;
        float dv = v - q0.y;
        float pw = fmaf(q0.z * du, du, fmaf(q0.w * dv, dv, q1.x * (du * dv)));
        bool hit = (pw <= 0.0f) && (pw >= q1.z);
        if (__any(hit)) {
            float e  = expf(pw);
            float al = hit ? fminf(0.99f, q1.y * e) : 0.0f;
            float w  = T * al;
            const float* f = featB + n * C_;
#pragma unroll
            for (int c = 0; c < C_; ++c) acc[c] = fmaf(w, f[c], acc[c]);
            T *= (1.0f - al);
        }
    }

    size_t obase = (size_t)b * C_ * H_ * W_ + (size_t)uu * W_ + vv;
#pragma unroll
    for (int c = 0; c < C_; ++c) out[obase + (size_t)c * (H_ * W_)] = acc[c];
}

extern "C" void kernel_launch(void* const* d_in, const int* in_sizes, int n_in,
                              void* d_out, int out_size, void* d_ws, size_t ws_size,
                              hipStream_t stream) {
    const float* features  = (const float*)d_in[0];
    const float* means3D   = (const float*)d_in[1];
    const float* cov3D     = (const float*)d_in[2];
    const float* opacities = (const float*)d_in[3];
    float* out = (float*)d_out;

    bool use_ws = (ws_size >= (size_t)B_ * N_ * 8 * sizeof(float));
    float4* params = use_ws ? (float4*)d_ws : nullptr;

    precompute_kernel<<<1, 1024, 0, stream>>>(means3D, cov3D, opacities, params,
                                              out + OUT_BEV);
    if (use_ws) {
        render_kernel<<<1250, 64, 0, stream>>>(features, params, out);
    } else {
        render_kernel_lds<<<1250, 64, 0, stream>>>(features, means3D, cov3D,
                                                   opacities, out);
    }
}

// Round 2
// 27.177 us; speedup vs baseline: 3.7518x; 3.7518x over previous
//
#include <hip/hip_runtime.h>
#include <math.h>

#define B_ 2
#define N_ 512
#define C_ 32
#define H_ 200
#define W_ 200
#define THRESH_ 0.05f
#define OUT_BEV (B_*C_*H_*W_)
#define NSEG 4
#define SEG (N_/NSEG)            // 128 gaussians per wave
#define TILES_PER_B 625          // 25x25 tiles of 8x8

// power = a*du^2 + bb*dv^2 + cc*du*dv ; contribute iff 0 >= power >= thr
__device__ inline void compute_params(float x, float y, float c0, float c1, float c3,
                                      float op, float4& q0, float4& q1, float4& bb4) {
    float mu_u = 100.0f - 100.0f * y;
    float mu_v = 100.0f - 100.0f * x;
    float Cuu = 10000.0f * c3 + 0.3f;
    float Cvv = 10000.0f * c0 + 0.3f;
    float Cuv = 10000.0f * c1;
    float det = Cuu * Cvv - Cuv * Cuv;
    bool valid = det > 0.0f;
    float opac = (op > THRESH_) ? op : 0.0f;
    if (!valid) opac = 0.0f;
    float inv_det = valid ? (1.0f / det) : 0.0f;
    float a  = -0.5f * (Cvv * inv_det);
    float bb = -0.5f * (Cuu * inv_det);
    float cc = Cuv * inv_det;
    float thr, r;
    if (opac > 0.0f) { r = logf(255.0f * opac); thr = -r; }
    else             { r = 0.0f;                thr = 3.0e38f; }
    q0 = make_float4(mu_u, mu_v, a, bb);
    q1 = make_float4(cc, opac, thr, 0.0f);
    if (opac > 0.0f) {
        // exact extent of {power >= thr}: |du| <= sqrt(2 r Cuu), |dv| <= sqrt(2 r Cvv)
        float du_max = sqrtf(2.0f * r * Cuu) + 1.0e-3f;
        float dv_max = sqrtf(2.0f * r * Cvv) + 1.0e-3f;
        bb4 = make_float4(mu_u - du_max, mu_u + du_max, mu_v - dv_max, mu_v + dv_max);
    } else {
        bb4 = make_float4(1.0e30f, -1.0e30f, 1.0e30f, -1.0e30f);   // empty
    }
}

// One block of 1024 threads: params + bbox -> ws, count scalar -> d_out tail.
__global__ __launch_bounds__(1024) void precompute_kernel(
    const float* __restrict__ means3D,
    const float* __restrict__ cov3D,
    const float* __restrict__ opacities,
    float4* __restrict__ params,          // [B*N*2]
    float4* __restrict__ bbox,            // [B*N]
    float* __restrict__ out_scalar)
{
    int i = threadIdx.x;                  // b*N + n
    float x  = means3D[i*3 + 0];
    float y  = means3D[i*3 + 1];
    float c0 = cov3D[i*6 + 0];
    float c1 = cov3D[i*6 + 1];
    float c3 = cov3D[i*6 + 3];
    float op = opacities[i];

    if (params) {
        float4 q0, q1, bb4;
        compute_params(x, y, c0, c1, c3, op, q0, q1, bb4);
        params[2*i]     = q0;
        params[2*i + 1] = q1;
        bbox[i]         = bb4;
    }

    __shared__ int red[1024];
    red[i] = (op > THRESH_) ? 1 : 0;
    __syncthreads();
    for (int s = 512; s > 0; s >>= 1) {
        if (i < s) red[i] += red[i + s];
        __syncthreads();
    }
    if (i == 0) out_scalar[0] = (float)red[0] / (float)B_;
}

// Block = 4 waves on one 8x8 tile; wave g composites gaussians [g*128,(g+1)*128)
// via ballot-based bbox culling; ordered combine through LDS.
__global__ __launch_bounds__(256) void render_kernel(
    const float* __restrict__ features,   // [B,N,C]
    const float4* __restrict__ params,    // [B*N*2]
    const float4* __restrict__ bbox,      // [B*N]
    float* __restrict__ out)              // [B,C,H,W]
{
    __shared__ float s_acc[NSEG][C_][64];   // [seg][chan][pixel] — stride-1 lanes
    __shared__ float s_T[NSEG][64];
    __shared__ float s_W[NSEG][64];

    int blk = blockIdx.x;
    int b  = blk / TILES_PER_B;
    int t  = blk - b * TILES_PER_B;
    int tu = t / 25;
    int tv = t - tu * 25;
    int tid  = threadIdx.x;
    int wave = tid >> 6;
    int lane = tid & 63;
    int uu = tu * 8 + (lane >> 3);
    int vv = tv * 8 + (lane & 7);
    float u = (float)uu, v = (float)vv;
    float tu0 = (float)(tu * 8), tu1 = tu0 + 7.0f;
    float tv0 = (float)(tv * 8), tv1 = tv0 + 7.0f;

    float T = 1.0f;
    float acc[C_];
#pragma unroll
    for (int c = 0; c < C_; ++c) acc[c] = 0.0f;

    const float*  featB = features + (size_t)b * N_ * C_;
    const float4* pb    = params + (size_t)b * N_ * 2;
    const float4* bbB   = bbox + (size_t)b * N_;

    int n0 = wave * SEG;
    for (int base = n0; base < n0 + SEG; base += 64) {
        float4 bx = bbB[base + lane];     // (umin, umax, vmin, vmax)
        bool ov = (bx.x <= tu1) & (bx.y >= tu0) & (bx.z <= tv1) & (bx.w >= tv0);
        unsigned long long mask = __ballot(ov);
        while (mask) {
            int j = __builtin_ctzll(mask);   // increasing n -> order preserved
            mask &= (mask - 1);
            int n = base + j;                // wave-uniform
            float4 q0 = pb[2*n];
            float4 q1 = pb[2*n + 1];
            float du = u - q0.x;
            float dv = v - q0.y;
            float pw = fmaf(q0.z * du, du, fmaf(q0.w * dv, dv, q1.x * (du * dv)));
            bool hit = (pw <= 0.0f) && (pw >= q1.z);
            if (__any(hit)) {
                float al = hit ? fminf(0.99f, q1.y * __expf(pw)) : 0.0f;
                float w  = T * al;
                const float* f = featB + n * C_;
#pragma unroll
                for (int c = 0; c < C_; ++c) acc[c] = fmaf(w, f[c], acc[c]);
                T *= (1.0f - al);
            }
        }
    }

    // stage partials
#pragma unroll
    for (int c = 0; c < C_; ++c) s_acc[wave][c][lane] = acc[c];
    s_T[wave][lane] = T;
    __syncthreads();

    // prefix transmittance weight for this wave's segment (pixel = lane)
    float Wg = 1.0f;
    for (int g = 0; g < wave; ++g) Wg *= s_T[g][lane];
    s_W[wave][lane] = Wg;
    __syncthreads();

    // combine + write: 2048 (c,p) pairs over 256 threads = 8 each
    size_t obase = (size_t)b * C_ * H_ * W_ + (size_t)(tu * 8) * W_ + (size_t)(tv * 8);
#pragma unroll
    for (int k = 0; k < 8; ++k) {
        int c = k * 4 + wave;
        float val = 0.0f;
#pragma unroll
        for (int g = 0; g < NSEG; ++g) val = fmaf(s_W[g][lane], s_acc[g][c][lane], val);
        out[obase + (size_t)c * (H_ * W_) + (size_t)(lane >> 3) * W_ + (lane & 7)] = val;
    }
}

// Fallback when ws is too small: one wave per tile, params in LDS (round-1 path).
__global__ __launch_bounds__(64) void render_kernel_lds(
    const float* __restrict__ features,
    const float* __restrict__ means3D,
    const float* __restrict__ cov3D,
    const float* __restrict__ opacities,
    float* __restrict__ out)
{
    __shared__ float4 p0[N_];
    __shared__ float4 p1[N_];

    int blk = blockIdx.x;
    int b  = blk / TILES_PER_B;
    int t  = blk - b * TILES_PER_B;
    int tu = t / 25;
    int tv = t - tu * 25;
    int lane = threadIdx.x;

    for (int n = lane; n < N_; n += 64) {
        int i = b * N_ + n;
        float4 q0, q1, bb4;
        compute_params(means3D[i*3+0], means3D[i*3+1],
                       cov3D[i*6+0], cov3D[i*6+1], cov3D[i*6+3],
                       opacities[i], q0, q1, bb4);
        p0[n] = q0;
        p1[n] = q1;
    }
    __syncthreads();

    int uu = tu * 8 + (lane >> 3);
    int vv = tv * 8 + (lane & 7);
    float u = (float)uu, v = (float)vv;

    float T = 1.0f;
    float acc[C_];
#pragma unroll
    for (int c = 0; c < C_; ++c) acc[c] = 0.0f;

    const float* featB = features + (size_t)b * N_ * C_;

    for (int n = 0; n < N_; ++n) {
        float4 q0 = p0[n];
        float4 q1 = p1[n];
        float du = u - q0.x;
        float dv = v - q0.y;
        float pw = fmaf(q0.z * du, du, fmaf(q0.w * dv, dv, q1.x * (du * dv)));
        bool hit = (pw <= 0.0f) && (pw >= q1.z);
        if (__any(hit)) {
            float al = hit ? fminf(0.99f, q1.y * __expf(pw)) : 0.0f;
            float w  = T * al;
            const float* f = featB + n * C_;
#pragma unroll
            for (int c = 0; c < C_; ++c) acc[c] = fmaf(w, f[c], acc[c]);
            T *= (1.0f - al);
        }
    }

    size_t obase = (size_t)b * C_ * H_ * W_ + (size_t)uu * W_ + vv;
#pragma unroll
    for (int c = 0; c < C_; ++c) out[obase + (size_t)c * (H_ * W_)] = acc[c];
}

extern "C" void kernel_launch(void* const* d_in, const int* in_sizes, int n_in,
                              void* d_out, int out_size, void* d_ws, size_t ws_size,
                              hipStream_t stream) {
    const float* features  = (const float*)d_in[0];
    const float* means3D   = (const float*)d_in[1];
    const float* cov3D     = (const float*)d_in[2];
    const float* opacities = (const float*)d_in[3];
    float* out = (float*)d_out;

    // ws layout: params [B*N*2] float4 (32 KB) + bbox [B*N] float4 (16 KB)
    size_t need = (size_t)B_ * N_ * 3 * sizeof(float4);
    bool use_ws = (ws_size >= need);
    float4* params = use_ws ? (float4*)d_ws : nullptr;
    float4* bbx    = use_ws ? params + (size_t)B_ * N_ * 2 : nullptr;

    precompute_kernel<<<1, 1024, 0, stream>>>(means3D, cov3D, opacities, params,
                                              bbx, out + OUT_BEV);
    if (use_ws) {
        render_kernel<<<B_ * TILES_PER_B, 256, 0, stream>>>(features, params, bbx, out);
    } else {
        render_kernel_lds<<<B_ * TILES_PER_B, 64, 0, stream>>>(features, means3D, cov3D,
                                                               opacities, out);
    }
}

// Round 3
// 23.966 us; speedup vs baseline: 4.2544x; 1.1340x over previous
//
#include <hip/hip_runtime.h>
#include <math.h>

#define B_ 2
#define N_ 512
#define C_ 32
#define H_ 200
#define W_ 200
#define HW_ (H_*W_)
#define THRESH_ 0.05f
#define OUT_BEV (B_*C_*H_*W_)
#define NSEG 8                    // 8 waves/block, 64 gaussians each
#define TILES_PER_B 625           // 25x25 tiles of 8x8
#define LOG2E 1.4426950408889634f
#define LN2   0.6931471805599453f

// Single fused kernel. Blocks 0..1249: one 8x8 tile each (8 waves, ordered
// segment compositing). Block 1250: num_gaussians scalar only.
__global__ __launch_bounds__(512, 2) void render_kernel(
    const float* __restrict__ features,   // [B,N,C]
    const float* __restrict__ means3D,    // [B,N,3]
    const float* __restrict__ cov3D,      // [B,N,6]
    const float* __restrict__ opacities,  // [B,N,1]
    float* __restrict__ out)              // [B,C,H,W] + 1 scalar
{
    // LDS: params 16 KB + s_T 2 KB + union{ bbox 8 KB | s_W 2 KB + s_acc 16 KB }
    __shared__ float4 p0[N_];             // mu_u, mu_v, a2, b2  (log2-domain quad)
    __shared__ float4 p1[N_];             // c2, opac, thr2, -
    __shared__ float  s_T[NSEG][64];
    __shared__ alignas(16) char u_mem[18432];
    float4* s_bb = (float4*)u_mem;                            // [512]
    float*  s_W  = (float*)u_mem;                             // [8*64]
    float (*s_acc)[NSEG][64] = (float (*)[NSEG][64])(u_mem + 2048); // [8][8][64]

    int blk = blockIdx.x;
    int tid = threadIdx.x;

    if (blk == B_ * TILES_PER_B) {        // ---- count-only block ----
        float op0 = opacities[tid];
        float op1 = opacities[N_ + tid];
        int cnt = (op0 > THRESH_ ? 1 : 0) + (op1 > THRESH_ ? 1 : 0);
        for (int off = 32; off > 0; off >>= 1) cnt += __shfl_down(cnt, off);
        int* s_red = (int*)s_T;
        if ((tid & 63) == 0) s_red[tid >> 6] = cnt;
        __syncthreads();
        if (tid == 0) {
            int tot = 0;
            for (int g = 0; g < NSEG; ++g) tot += s_red[g];
            out[OUT_BEV] = (float)tot * 0.5f;
        }
        return;
    }

    int b  = blk / TILES_PER_B;
    int t  = blk - b * TILES_PER_B;
    int tu = t / 25;
    int tv = t - tu * 25;

    // ---- prologue: per-block param recompute (tid = gaussian index) ----
    {
        int i = b * N_ + tid;
        float x  = means3D[i*3 + 0];
        float y  = means3D[i*3 + 1];
        float c0 = cov3D[i*6 + 0];
        float c1 = cov3D[i*6 + 1];
        float c3 = cov3D[i*6 + 3];
        float op = opacities[i];
        float mu_u = 100.0f - 100.0f * y;
        float mu_v = 100.0f - 100.0f * x;
        float Cuu = 10000.0f * c3 + 0.3f;
        float Cvv = 10000.0f * c0 + 0.3f;
        float Cuv = 10000.0f * c1;
        float det = Cuu * Cvv - Cuv * Cuv;
        bool valid = det > 0.0f;
        float opac = (op > THRESH_) ? op : 0.0f;
        if (!valid) opac = 0.0f;
        float inv_det = valid ? (1.0f / det) : 0.0f;
        float a2 = -0.5f * LOG2E * (Cvv * inv_det);
        float b2 = -0.5f * LOG2E * (Cuu * inv_det);
        float c2 =  LOG2E * (Cuv * inv_det);          // -Iuv * log2e
        float thr2;
        float4 bb4;
        if (opac > 0.0f) {
            float r2 = log2f(255.0f * opac);          // > 0 since opac > 0.05
            thr2 = -r2;
            float rn = LN2 * r2;                      // natural-log radius
            float du_max = sqrtf(fmaxf(2.0f * rn * Cuu, 0.0f)) + 1.0e-3f;
            float dv_max = sqrtf(fmaxf(2.0f * rn * Cvv, 0.0f)) + 1.0e-3f;
            bb4 = make_float4(mu_u - du_max, mu_u + du_max, mu_v - dv_max, mu_v + dv_max);
        } else {
            thr2 = 3.0e38f;
            bb4 = make_float4(1.0e30f, -1.0e30f, 1.0e30f, -1.0e30f);
        }
        p0[tid]   = make_float4(mu_u, mu_v, a2, b2);
        p1[tid]   = make_float4(c2, opac, thr2, 0.0f);
        s_bb[tid] = bb4;
    }
    __syncthreads();   // sync #1: params + bbox visible

    int wave = tid >> 6;
    int lane = tid & 63;
    int uu = tu * 8 + (lane >> 3);
    int vv = tv * 8 + (lane & 7);
    float u = (float)uu, v = (float)vv;
    float tu0 = (float)(tu * 8), tu1 = tu0 + 7.0f;
    float tv0 = (float)(tv * 8), tv1 = tv0 + 7.0f;

    // ---- cull: one ballot, each lane owns one gaussian of this segment ----
    int base = wave * 64;
    float4 bx = s_bb[base + lane];
    bool ov = (bx.x <= tu1) & (bx.y >= tu0) & (bx.z <= tv1) & (bx.w >= tv0);
    unsigned long long mask = __ballot(ov);

    float T = 1.0f;
    float acc[C_];
#pragma unroll
    for (int c = 0; c < C_; ++c) acc[c] = 0.0f;
    const float* featB = features + (size_t)b * N_ * C_;

    // ---- ordered hit loop (params broadcast from LDS) ----
    while (mask) {
        int j = __builtin_ctzll(mask);
        mask &= (mask - 1);
        int n = base + j;                 // wave-uniform
        float4 q0 = p0[n];
        float4 q1 = p1[n];
        float du = u - q0.x;
        float dv = v - q0.y;
        float pw = fmaf(q0.z * du, du, fmaf(q0.w * dv, dv, q1.x * (du * dv)));
        bool hit = (pw <= 0.0f) && (pw >= q1.z);
        if (__any(hit)) {
            float al = hit ? fminf(0.99f, q1.y * exp2f(pw)) : 0.0f;
            float w  = T * al;
            const float* f = featB + n * C_;
#pragma unroll
            for (int c = 0; c < C_; ++c) acc[c] = fmaf(w, f[c], acc[c]);
            T *= (1.0f - al);
        }
    }

    // ---- combine: prefix transmittance, 4 channel-rounds through LDS ----
    s_T[wave][lane] = T;
    __syncthreads();   // sync #2: all hit loops done; s_bb now dead (union safe)

    {
        float Wg = 1.0f;
        for (int gp = 0; gp < wave; ++gp) Wg *= s_T[gp][lane];
        s_W[wave * 64 + lane] = Wg;
    }

    size_t obase = (size_t)b * C_ * HW_ + (size_t)(tu * 8) * W_ + (size_t)(tv * 8);
#pragma unroll
    for (int k = 0; k < 4; ++k) {
#pragma unroll
        for (int c = 0; c < 8; ++c) s_acc[wave][c][lane] = acc[k * 8 + c];
        __syncthreads();               // covers s_W on k==0, s_acc each round
        float val = 0.0f;
#pragma unroll
        for (int g = 0; g < NSEG; ++g)
            val = fmaf(s_W[g * 64 + lane], s_acc[g][wave][lane], val);
        int c = k * 8 + wave;
        out[obase + (size_t)c * HW_ + (size_t)(lane >> 3) * W_ + (lane & 7)] = val;
        if (k < 3) __syncthreads();    // before next round overwrites s_acc
    }
}

extern "C" void kernel_launch(void* const* d_in, const int* in_sizes, int n_in,
                              void* d_out, int out_size, void* d_ws, size_t ws_size,
                              hipStream_t stream) {
    const float* features  = (const float*)d_in[0];
    const float* means3D   = (const float*)d_in[1];
    const float* cov3D     = (const float*)d_in[2];
    const float* opacities = (const float*)d_in[3];
    float* out = (float*)d_out;
    render_kernel<<<B_ * TILES_PER_B + 1, 512, 0, stream>>>(
        features, means3D, cov3D, opacities, out);
}

// Round 4
// 17.286 us; speedup vs baseline: 5.8984x; 1.3864x over previous
//
#include <hip/hip_runtime.h>
#include <math.h>

#define B_ 2
#define N_ 512
#define C_ 32
#define H_ 200
#define W_ 200
#define HW_ (H_*W_)
#define THRESH_ 0.05f
#define OUT_BEV (B_*C_*H_*W_)
#define NSEG 8                    // 8 waves/block, 64 gaussians each
#define TILES_PER_B 625           // 25x25 tiles of 8x8
#define LOG2E 1.4426950408889634f
#define LN2   0.6931471805599453f

__device__ inline float rlane(float x, int l) {
    return __int_as_float(__builtin_amdgcn_readlane(__float_as_int(x), l));
}

// Single fused kernel. Blocks 0..1249: one 8x8 tile (8 waves, ordered segment
// compositing, params lane-resident + readlane broadcast). Block 1250: count.
__global__ __launch_bounds__(512, 4) void render_kernel(
    const float* __restrict__ features,   // [B,N,C]
    const float* __restrict__ means3D,    // [B,N,3]
    const float* __restrict__ cov3D,      // [B,N,6]
    const float* __restrict__ opacities,  // [B,N,1]
    float* __restrict__ out)              // [B,C,H,W] + 1 scalar
{
    __shared__ float s_T[NSEG][64];             // 2 KB
    __shared__ float s_W[NSEG * 64];            // 2 KB
    __shared__ float s_acc[NSEG][NSEG][64];     // 16 KB

    int blk = blockIdx.x;
    int tid = threadIdx.x;

    if (blk == B_ * TILES_PER_B) {        // ---- count-only block ----
        float op0 = opacities[tid];
        float op1 = opacities[N_ + tid];
        int cnt = (op0 > THRESH_ ? 1 : 0) + (op1 > THRESH_ ? 1 : 0);
        for (int off = 32; off > 0; off >>= 1) cnt += __shfl_down(cnt, off);
        int* s_red = (int*)s_W;
        if ((tid & 63) == 0) s_red[tid >> 6] = cnt;
        __syncthreads();
        if (tid == 0) {
            int tot = 0;
            for (int g = 0; g < NSEG; ++g) tot += s_red[g];
            out[OUT_BEV] = (float)tot * 0.5f;
        }
        return;
    }

    int b  = blk / TILES_PER_B;
    int t  = blk - b * TILES_PER_B;
    int tu = t / 25;
    int tv = t - tu * 25;
    int wave = __builtin_amdgcn_readfirstlane(tid >> 6);   // uniform!
    int lane = tid & 63;

    // ---- per-lane param compute: lane owns gaussian (wave*64 + lane) ----
    float g_mu_u, g_mu_v, g_a2, g_b2, g_c2, g_op, g_thr2;
    bool ov;
    {
        int i = b * N_ + wave * 64 + lane;
        float x  = means3D[i*3 + 0];
        float y  = means3D[i*3 + 1];
        float c0 = cov3D[i*6 + 0];
        float c1 = cov3D[i*6 + 1];
        float c3 = cov3D[i*6 + 3];
        float op = opacities[i];
        g_mu_u = 100.0f - 100.0f * y;
        g_mu_v = 100.0f - 100.0f * x;
        float Cuu = 10000.0f * c3 + 0.3f;
        float Cvv = 10000.0f * c0 + 0.3f;
        float Cuv = 10000.0f * c1;
        float det = Cuu * Cvv - Cuv * Cuv;
        bool valid = det > 0.0f;
        float opac = (op > THRESH_) ? op : 0.0f;
        if (!valid) opac = 0.0f;
        float inv_det = valid ? (1.0f / det) : 0.0f;
        g_a2 = -0.5f * LOG2E * (Cvv * inv_det);
        g_b2 = -0.5f * LOG2E * (Cuu * inv_det);
        g_c2 =  LOG2E * (Cuv * inv_det);
        g_op = opac;
        float tu0 = (float)(tu * 8), tu1 = tu0 + 7.0f;
        float tv0 = (float)(tv * 8), tv1 = tv0 + 7.0f;
        if (opac > 0.0f) {
            float r2 = log2f(255.0f * opac);            // > 0 since opac > .05
            g_thr2 = -r2;
            float rn = LN2 * r2;
            float du_max = sqrtf(fmaxf(2.0f * rn * Cuu, 0.0f)) + 1.0e-3f;
            float dv_max = sqrtf(fmaxf(2.0f * rn * Cvv, 0.0f)) + 1.0e-3f;
            ov = (g_mu_u - du_max <= tu1) & (g_mu_u + du_max >= tu0) &
                 (g_mu_v - dv_max <= tv1) & (g_mu_v + dv_max >= tv0);
        } else {
            g_thr2 = 3.0e38f;
            ov = false;
        }
    }
    unsigned long long mask = __ballot(ov);

    int uu = tu * 8 + (lane >> 3);
    int vv = tv * 8 + (lane & 7);
    float u = (float)uu, v = (float)vv;

    float T = 1.0f;
    float acc[C_];
#pragma unroll
    for (int c = 0; c < C_; ++c) acc[c] = 0.0f;
    const float* featB = features + (size_t)b * (N_ * C_);
    int base_n = wave * 64;                                // uniform

    // ---- ordered hit loop: params via readlane, features via s_load ----
    while (mask) {
        int j = __builtin_ctzll(mask);                     // uniform
        mask &= (mask - 1);
        float qmu_u = rlane(g_mu_u, j);
        float qmu_v = rlane(g_mu_v, j);
        float qa    = rlane(g_a2,   j);
        float qb    = rlane(g_b2,   j);
        float qc    = rlane(g_c2,   j);
        float qop   = rlane(g_op,   j);
        float qthr  = rlane(g_thr2, j);
        int n = base_n + j;                                // uniform
        const float* f = featB + (size_t)n * C_;           // uniform -> s_load
        float du = u - qmu_u;
        float dv = v - qmu_v;
        float pw = fmaf(qa * du, du, fmaf(qb * dv, dv, qc * (du * dv)));
        bool hit = (pw <= 0.0f) && (pw >= qthr);
        if (__any(hit)) {
            float al = hit ? fminf(0.99f, qop * exp2f(pw)) : 0.0f;
            float w  = T * al;
#pragma unroll
            for (int c = 0; c < C_; ++c) acc[c] = fmaf(w, f[c], acc[c]);
            T *= (1.0f - al);
        }
    }

    // ---- combine: prefix transmittance, 4 channel-rounds through LDS ----
    s_T[wave][lane] = T;
    __syncthreads();

    {
        float Wg = 1.0f;
        for (int gp = 0; gp < wave; ++gp) Wg *= s_T[gp][lane];
        s_W[wave * 64 + lane] = Wg;
    }

    size_t obase = (size_t)b * C_ * HW_ + (size_t)(tu * 8) * W_ + (size_t)(tv * 8);
#pragma unroll
    for (int k = 0; k < 4; ++k) {
#pragma unroll
        for (int c = 0; c < 8; ++c) s_acc[wave][c][lane] = acc[k * 8 + c];
        __syncthreads();               // covers s_W on k==0, s_acc each round
        float val = 0.0f;
#pragma unroll
        for (int g = 0; g < NSEG; ++g)
            val = fmaf(s_W[g * 64 + lane], s_acc[g][wave][lane], val);
        int c = k * 8 + wave;
        out[obase + (size_t)c * HW_ + (size_t)(lane >> 3) * W_ + (lane & 7)] = val;
        if (k < 3) __syncthreads();    // before next round overwrites s_acc
    }
}

extern "C" void kernel_launch(void* const* d_in, const int* in_sizes, int n_in,
                              void* d_out, int out_size, void* d_ws, size_t ws_size,
                              hipStream_t stream) {
    const float* features  = (const float*)d_in[0];
    const float* means3D   = (const float*)d_in[1];
    const float* cov3D     = (const float*)d_in[2];
    const float* opacities = (const float*)d_in[3];
    float* out = (float*)d_out;
    render_kernel<<<B_ * TILES_PER_B + 1, 512, 0, stream>>>(
        features, means3D, cov3D, opacities, out);
}

// Round 5
// 16.912 us; speedup vs baseline: 6.0288x; 1.0221x over previous
//
#include <hip/hip_runtime.h>
#include <math.h>

#define B_ 2
#define N_ 512
#define C_ 32
#define H_ 200
#define W_ 200
#define HW_ (H_*W_)
#define THRESH_ 0.05f
#define OUT_BEV (B_*C_*H_*W_)
#define NSEG 4                    // 4 waves/block, 128 gaussians each
#define TILES_PER_B 625           // 25x25 tiles of 8x8
#define LOG2E 1.4426950408889634f
#define LN2   0.6931471805599453f

__device__ __forceinline__ float rlane(float x, int l) {
    return __int_as_float(__builtin_amdgcn_readlane(__float_as_int(x), l));
}

// Per-lane gaussian param compute + tile-overlap test (exact ellipse bbox).
__device__ __forceinline__ bool pcompute(
    const float* __restrict__ m3, const float* __restrict__ cv,
    const float* __restrict__ opc, int i,
    float tu0, float tu1, float tv0, float tv1,
    float& mu_u, float& mu_v, float& a2, float& b2, float& c2,
    float& opo, float& thr2)
{
    float x  = m3[i*3 + 0];
    float y  = m3[i*3 + 1];
    float c0 = cv[i*6 + 0];
    float c1 = cv[i*6 + 1];
    float c3 = cv[i*6 + 3];
    float op = opc[i];
    mu_u = 100.0f - 100.0f * y;
    mu_v = 100.0f - 100.0f * x;
    float Cuu = 10000.0f * c3 + 0.3f;
    float Cvv = 10000.0f * c0 + 0.3f;
    float Cuv = 10000.0f * c1;
    float det = Cuu * Cvv - Cuv * Cuv;
    bool valid = det > 0.0f;
    float opac = (op > THRESH_) ? op : 0.0f;
    if (!valid) opac = 0.0f;
    float inv_det = valid ? (1.0f / det) : 0.0f;
    a2 = -0.5f * LOG2E * (Cvv * inv_det);
    b2 = -0.5f * LOG2E * (Cuu * inv_det);
    c2 =  LOG2E * (Cuv * inv_det);
    opo = opac;
    if (opac > 0.0f) {
        float r2 = log2f(255.0f * opac);          // > 0 since opac > 0.05
        thr2 = -r2;
        float rn = LN2 * r2;
        float du_max = sqrtf(fmaxf(2.0f * rn * Cuu, 0.0f)) + 1.0e-3f;
        float dv_max = sqrtf(fmaxf(2.0f * rn * Cvv, 0.0f)) + 1.0e-3f;
        return (mu_u - du_max <= tu1) & (mu_u + du_max >= tu0) &
               (mu_v - dv_max <= tv1) & (mu_v + dv_max >= tv0);
    }
    thr2 = 3.0e38f;
    return false;
}

// Walk a 64-bit hit mask two gaussians at a time (order preserved: ctz is
// ascending). Params broadcast via readlane (SGPRs); feature rows are
// wave-uniform -> s_load; both rows issued before the FMA block.
#define WALK(mask, P, base_n)                                                \
    while (mask) {                                                           \
        int j0 = __builtin_ctzll(mask); mask &= mask - 1;                    \
        bool two = (mask != 0ull);                                           \
        int j1 = two ? __builtin_ctzll(mask) : j0;                           \
        if (two) mask &= mask - 1;                                           \
        float mu_u0 = rlane(P##_mu_u, j0), mu_v0 = rlane(P##_mu_v, j0);      \
        float a0 = rlane(P##_a, j0), b0 = rlane(P##_b, j0);                  \
        float c0 = rlane(P##_c, j0), op0 = rlane(P##_op, j0);                \
        float th0 = rlane(P##_th, j0);                                       \
        float mu_u1 = rlane(P##_mu_u, j1), mu_v1 = rlane(P##_mu_v, j1);      \
        float a1 = rlane(P##_a, j1), b1 = rlane(P##_b, j1);                  \
        float c1 = rlane(P##_c, j1), op1 = rlane(P##_op, j1);                \
        float th1 = rlane(P##_th, j1);                                       \
        const float* f0 = featB + (size_t)((base_n) + j0) * C_;              \
        const float* f1 = featB + (size_t)((base_n) + j1) * C_;              \
        float du0 = u - mu_u0, dv0 = v - mu_v0;                              \
        float pw0 = fmaf(a0 * du0, du0, fmaf(b0 * dv0, dv0, c0 * (du0 * dv0))); \
        bool hit0 = (pw0 <= 0.0f) && (pw0 >= th0);                           \
        float al0 = hit0 ? fminf(0.99f, op0 * exp2f(pw0)) : 0.0f;            \
        float du1 = u - mu_u1, dv1 = v - mu_v1;                              \
        float pw1 = fmaf(a1 * du1, du1, fmaf(b1 * dv1, dv1, c1 * (du1 * dv1))); \
        bool hit1 = two && (pw1 <= 0.0f) && (pw1 >= th1);                    \
        float al1 = hit1 ? fminf(0.99f, op1 * exp2f(pw1)) : 0.0f;            \
        if (__any(hit0 | hit1)) {                                            \
            float w0 = T * al0;                                              \
            float Tm = T * (1.0f - al0);                                     \
            float w1 = Tm * al1;                                             \
            T = Tm * (1.0f - al1);                                           \
            _Pragma("unroll")                                                \
            for (int c = 0; c < C_; ++c)                                     \
                acc[c] = fmaf(w1, f1[c], fmaf(w0, f0[c], acc[c]));           \
        }                                                                    \
    }

// Blocks 0..1249: one 8x8 tile each (4 waves x 128-gaussian ordered segments).
// Block 1250: num_gaussians scalar. All 1251 blocks co-resident at 5 blk/CU.
__global__ __launch_bounds__(256, 5) void render_kernel(
    const float* __restrict__ features,   // [B,N,C]
    const float* __restrict__ means3D,    // [B,N,3]
    const float* __restrict__ cov3D,      // [B,N,6]
    const float* __restrict__ opacities,  // [B,N,1]
    float* __restrict__ out)              // [B,C,H,W] + 1 scalar
{
    __shared__ float s_T[NSEG][64];          // 1 KB
    __shared__ float s_W[NSEG * 64];         // 1 KB
    __shared__ float s_acc[NSEG][8][64];     // 8 KB

    int blk = blockIdx.x;
    int tid = threadIdx.x;

    if (blk == B_ * TILES_PER_B) {           // ---- count-only block ----
        int cnt = ((opacities[tid]       > THRESH_) ? 1 : 0)
                + ((opacities[tid + 256] > THRESH_) ? 1 : 0)
                + ((opacities[tid + 512] > THRESH_) ? 1 : 0)
                + ((opacities[tid + 768] > THRESH_) ? 1 : 0);
        for (int off = 32; off > 0; off >>= 1) cnt += __shfl_down(cnt, off);
        int* s_red = (int*)s_W;
        if ((tid & 63) == 0) s_red[tid >> 6] = cnt;
        __syncthreads();
        if (tid == 0)
            out[OUT_BEV] = (float)(s_red[0] + s_red[1] + s_red[2] + s_red[3]) * 0.5f;
        return;
    }

    int b  = blk / TILES_PER_B;
    int t  = blk - b * TILES_PER_B;
    int tu = t / 25;
    int tv = t - tu * 25;
    int wave = __builtin_amdgcn_readfirstlane(tid >> 6);   // uniform
    int lane = tid & 63;

    float tu0 = (float)(tu * 8), tu1 = tu0 + 7.0f;
    float tv0 = (float)(tv * 8), tv1 = tv0 + 7.0f;

    // ---- per-lane params for the wave's two 64-gaussian halves ----
    float A_mu_u, A_mu_v, A_a, A_b, A_c, A_op, A_th;
    float B_mu_u, B_mu_v, B_a, B_b, B_c, B_op, B_th;
    int i0 = b * N_ + wave * 128 + lane;
    bool ovA = pcompute(means3D, cov3D, opacities, i0,      tu0, tu1, tv0, tv1,
                        A_mu_u, A_mu_v, A_a, A_b, A_c, A_op, A_th);
    bool ovB = pcompute(means3D, cov3D, opacities, i0 + 64, tu0, tu1, tv0, tv1,
                        B_mu_u, B_mu_v, B_a, B_b, B_c, B_op, B_th);
    unsigned long long m0 = __ballot(ovA);
    unsigned long long m1 = __ballot(ovB);

    int uu = tu * 8 + (lane >> 3);
    int vv = tv * 8 + (lane & 7);
    float u = (float)uu, v = (float)vv;

    float T = 1.0f;
    float acc[C_];
#pragma unroll
    for (int c = 0; c < C_; ++c) acc[c] = 0.0f;
    const float* featB = features + (size_t)b * (N_ * C_);

    // ---- ordered hit loops: first half then second half of the segment ----
    WALK(m0, A, wave * 128)
    WALK(m1, B, wave * 128 + 64)

    // ---- combine: prefix transmittance + 4 channel-rounds through LDS ----
    s_T[wave][lane] = T;
    __syncthreads();

    {
        float Wg = 1.0f;
        for (int g = 0; g < wave; ++g) Wg *= s_T[g][lane];
        s_W[wave * 64 + lane] = Wg;
    }

    size_t obase = (size_t)b * C_ * HW_ + (size_t)(tu * 8) * W_ + (size_t)(tv * 8);
    size_t opix  = (size_t)(lane >> 3) * W_ + (lane & 7);
#pragma unroll
    for (int k = 0; k < 4; ++k) {
#pragma unroll
        for (int cc = 0; cc < 8; ++cc) s_acc[wave][cc][lane] = acc[k * 8 + cc];
        __syncthreads();               // covers s_W on k==0, s_acc each round
        float v0 = 0.0f, v1 = 0.0f;
#pragma unroll
        for (int g = 0; g < NSEG; ++g) {
            float wgt = s_W[g * 64 + lane];
            v0 = fmaf(wgt, s_acc[g][wave][lane],     v0);
            v1 = fmaf(wgt, s_acc[g][wave + 4][lane], v1);
        }
        out[obase + (size_t)(k * 8 + wave) * HW_ + opix]     = v0;
        out[obase + (size_t)(k * 8 + wave + 4) * HW_ + opix] = v1;
        if (k < 3) __syncthreads();    // before next round overwrites s_acc
    }
}

extern "C" void kernel_launch(void* const* d_in, const int* in_sizes, int n_in,
                              void* d_out, int out_size, void* d_ws, size_t ws_size,
                              hipStream_t stream) {
    const float* features  = (const float*)d_in[0];
    const float* means3D   = (const float*)d_in[1];
    const float* cov3D     = (const float*)d_in[2];
    const float* opacities = (const float*)d_in[3];
    float* out = (float*)d_out;
    render_kernel<<<B_ * TILES_PER_B + 1, 256, 0, stream>>>(
        features, means3D, cov3D, opacities, out);
}